// Round 16
// baseline (101.516 us; speedup 1.0000x reference)
//
#include <hip/hip_runtime.h>
#include <hip/hip_bf16.h>

// ---------------------------------------------------------------------------
// CMHSAttn v14: fp32 in/out. R10-R15 elimination matrix: attn immune to every
// instruction-mix change at fixed 4 waves/SIMD -> TLP-bound (grid too small),
// not port-bound. v14: 2 q-tiles/wave (low VGPR) x SPLIT=8 = 2048 blocks =
// 8 waves/SIMD. l back on VALU+shfl (register diet). kv-interleaved zero-VALU
// addressing + cvt_pk pack retained from v13. qkv grid 256->512 blocks.
// ---------------------------------------------------------------------------

typedef __attribute__((ext_vector_type(4))) float    f32x4;
typedef __attribute__((ext_vector_type(8))) short    s16x8;
typedef __attribute__((ext_vector_type(4))) short    s16x4;
typedef __attribute__((ext_vector_type(8))) __bf16   bf16x8;
typedef __attribute__((ext_vector_type(4))) unsigned u32x4;

union FragAB { s16x8 s; bf16x8 b; u32x4 u; };

__device__ __forceinline__ short f2bf(float f) {
    unsigned u = __float_as_uint(f);
    u += 0x7fff + ((u >> 16) & 1);          // RNE
    return (short)(u >> 16);
}

__device__ __forceinline__ unsigned pkbf(float a, float b) {
    float2 f2; f2.x = a; f2.y = b;
    __hip_bfloat162 h = __float22bfloat162_rn(f2);   // v_cvt_pk_bf16_f32
    unsigned r;
    __builtin_memcpy(&r, &h, 4);                      // lo = a, hi = b
    return r;
}

#if __has_builtin(__builtin_amdgcn_exp2f)
  #define FASTEXP(x) __builtin_amdgcn_exp2f(x)
  #define QK_SCALE 0.12751744154070513f   // (1/sqrt(128)) * log2(e)
#else
  #define FASTEXP(x) __expf(x)
  #define QK_SCALE 0.08838834764831845f   // 1/sqrt(128)
#endif

// ---------------------------------------------------------------------------
// QKV: MFMA GEMM, grid (64 n-tiles, 8 o-eighths of 48) = 512 blocks.
// Q -> qT[h][n][16] (scaled). K,V -> interleaved kv buffer:
// kv[(h*64+T)*2048 + key_local*16 + d]                  (K region)
// kv[(h*64+T)*2048 + 1024 + d*64 + cc*32 + qp*8 + jj]   (V region, permuted:
//   key = T*64 + cc*32 + (jj>=4?16:0) + qp*4 + (jj&3) -- PV B-frag slot order)
// ---------------------------------------------------------------------------
__global__ __launch_bounds__(256) void qkv_kernel(
    const float* __restrict__ x, const float* __restrict__ w,
    short* __restrict__ qT, short* __restrict__ kv)
{
    __shared__ __align__(16) short xT[4][16][136];   // [wave][n][c], pad 8
    const int wv   = threadIdx.x >> 6;
    const int lane = threadIdx.x & 63;
    const int colL = lane & 15, quad = lane >> 4;
    const int n0 = blockIdx.x * 64 + wv * 16;
    const int oq = blockIdx.y;                        // 0..7

    #pragma unroll
    for (int rr = 0; rr < 4; ++rr) {
        int c  = rr * 32 + (lane >> 1);
        int nh = (lane & 1) * 8;
        f32x4 a = *(const f32x4*)&x[c * 4096 + n0 + nh];
        f32x4 b = *(const f32x4*)&x[c * 4096 + n0 + nh + 4];
        #pragma unroll
        for (int t = 0; t < 4; ++t) {
            xT[wv][nh + t][c]     = f2bf(a[t]);
            xT[wv][nh + 4 + t][c] = f2bf(b[t]);
        }
    }
    __syncthreads();

    FragAB xb[4];
    #pragma unroll
    for (int ks = 0; ks < 4; ++ks)
        xb[ks].s = *(const s16x8*)&xT[wv][colL][ks * 32 + quad * 8];

    const int T    = blockIdx.x;
    const int wloc = wv * 16 + colL;          // key_local = n & 63
    const int cc   = wloc >> 5;
    const int bb   = (wloc >> 4) & 1;
    const int qp   = (wloc >> 2) & 3;
    const int jj   = bb * 4 + (wloc & 3);

    #pragma unroll
    for (int i = 0; i < 3; ++i) {
        const int otg  = oq * 3 + i;          // 0..23
        const int ob   = otg * 16;
        const int h    = otg / 3;
        const int kind = otg % 3;             // 0=q, 1=k, 2=v
        f32x4 acc = {0.f, 0.f, 0.f, 0.f};
        #pragma unroll
        for (int ks = 0; ks < 4; ++ks) {
            f32x4 wa0 = *(const f32x4*)&w[(ob + colL) * 128 + ks * 32 + quad * 8];
            f32x4 wa1 = *(const f32x4*)&w[(ob + colL) * 128 + ks * 32 + quad * 8 + 4];
            FragAB wa;
            #pragma unroll
            for (int t = 0; t < 4; ++t) {
                wa.s[t]     = f2bf(wa0[t]);
                wa.s[t + 4] = f2bf(wa1[t]);
            }
            acc = __builtin_amdgcn_mfma_f32_16x16x32_bf16(wa.b, xb[ks].b, acc, 0, 0, 0);
        }
        // C: row = o_local = quad*4+r, col = n
        if (kind == 0) {
            s16x4 pk;
            #pragma unroll
            for (int r = 0; r < 4; ++r) pk[r] = f2bf(acc[r] * QK_SCALE);
            *(s16x4*)&qT[(h * 4096 + n0 + colL) * 16 + quad * 4] = pk;
        } else if (kind == 1) {
            s16x4 pk;
            #pragma unroll
            for (int r = 0; r < 4; ++r) pk[r] = f2bf(acc[r]);
            *(s16x4*)&kv[(h * 64 + T) * 2048 + wloc * 16 + quad * 4] = pk;
        } else {
            #pragma unroll
            for (int r = 0; r < 4; ++r) {
                int d = quad * 4 + r;
                kv[(h * 64 + T) * 2048 + 1024 + d * 64 + cc * 32 + qp * 8 + jj] = f2bf(acc[r]);
            }
        }
    }
}

// ---------------------------------------------------------------------------
// Attention v14: wave = 32 q (two 16-q tiles) x key chunk. SPLIT=8, nkt=8.
// 2048 blocks = 8192 waves = 8 waves/SIMD. Per kt: SGPR base advance + 6
// imm-offset loads; per pair: 4 QK MFMA -> 16 trans exp (+ VALU l-accum)
// -> 8 cvt_pk -> 2 PV MFMA.
// ---------------------------------------------------------------------------
template<int SPLIT>
__global__ __launch_bounds__(256) void attn_kernel(
    const short* __restrict__ qT, const short* __restrict__ kv,
    float* __restrict__ Opart, float* __restrict__ lpart,
    float* __restrict__ out)
{
    const int wv   = threadIdx.x >> 6;
    const int lane = threadIdx.x & 63;
    const int colL = lane & 15, quad = lane >> 4;

    const int bx = blockIdx.x;
    int s, h, b;
    if (SPLIT > 1) { s = bx >> 8; h = (bx >> 5) & 7; b = bx & 31; }
    else           { s = 0;       h = bx >> 5;       b = bx & 31; }
    const int qbase = b * 128 + wv * 32;     // this wave's 32 q rows
    const int nkt = 64 / SPLIT;

    FragAB qfs[2];                            // B-frags: Q^T[d][q], d<16
    #pragma unroll
    for (int u = 0; u < 2; ++u) {
        qfs[u].s = 0;
        if (quad < 2)
            qfs[u].s = *(const s16x8*)&qT[(h * 4096 + qbase + u * 16 + colL) * 16 + quad * 8];
    }

    f32x4 o[2];
    float l0[2], l1[2];
    #pragma unroll
    for (int u = 0; u < 2; ++u) {
        o[u] = (f32x4){0.f, 0.f, 0.f, 0.f};
        l0[u] = 0.f; l1[u] = 0.f;
    }

    // loop-invariant lane offsets (shorts)
    const int voffK = colL * 16 + quad * 8;          // + t*256
    const int voffV = 1024 + colL * 64 + quad * 8;   // + c*32

    const short* kvb = kv + (h * 64 + s * nkt) * 2048;

    #pragma unroll
    for (int kt = 0; kt < nkt; ++kt) {
        FragAB kf[4], vf[2];
        #pragma unroll
        for (int t = 0; t < 4; ++t)
            kf[t].s = *(const s16x8*)&kvb[voffK + t * 256];
        #pragma unroll
        for (int c = 0; c < 2; ++c)
            vf[c].s = *(const s16x8*)&kvb[voffV + c * 32];
        kvb += 2048;

        #pragma unroll
        for (int u = 0; u < 2; ++u) {
            f32x4 st[4];
            #pragma unroll
            for (int t = 0; t < 4; ++t) {
                f32x4 z = {0.f, 0.f, 0.f, 0.f};
                st[t] = __builtin_amdgcn_mfma_f32_16x16x32_bf16(kf[t].b, qfs[u].b, z, 0, 0, 0);
            }
            FragAB p0, p1;
            #pragma unroll
            for (int t = 0; t < 2; ++t) {
                float a0 = FASTEXP(st[t][0]),     a1 = FASTEXP(st[t][1]);
                float a2 = FASTEXP(st[t][2]),     a3 = FASTEXP(st[t][3]);
                float b0 = FASTEXP(st[t + 2][0]), b1 = FASTEXP(st[t + 2][1]);
                float b2 = FASTEXP(st[t + 2][2]), b3 = FASTEXP(st[t + 2][3]);
                l0[u] += (a0 + a2) + (b0 + b2);
                l1[u] += (a1 + a3) + (b1 + b3);
                p0.u[t * 2 + 0] = pkbf(a0, a1);
                p0.u[t * 2 + 1] = pkbf(a2, a3);
                p1.u[t * 2 + 0] = pkbf(b0, b1);
                p1.u[t * 2 + 1] = pkbf(b2, b3);
            }
            o[u] = __builtin_amdgcn_mfma_f32_16x16x32_bf16(vf[0].b, p0.b, o[u], 0, 0, 0);
            o[u] = __builtin_amdgcn_mfma_f32_16x16x32_bf16(vf[1].b, p1.b, o[u], 0, 0, 0);
        }
    }

    #pragma unroll
    for (int u = 0; u < 2; ++u) {
        float l = l0[u] + l1[u];
        l += __shfl_xor(l, 16, 64);
        l += __shfl_xor(l, 32, 64);
        const int q0 = qbase + u * 16;
        if (SPLIT > 1) {
            #pragma unroll
            for (int r = 0; r < 4; ++r)
                Opart[((s * 8 + h) * 16 + quad * 4 + r) * 4096 + q0 + colL] = o[u][r];
            if (quad == 0) lpart[(s * 8 + h) * 4096 + q0 + colL] = l;
        } else {
            const float inv = 1.f / l;
            #pragma unroll
            for (int r = 0; r < 4; ++r)
                out[(h * 16 + quad * 4 + r) * 4096 + q0 + colL] = o[u][r] * inv;
        }
    }
}

// ---------------------------------------------------------------------------
template<int SPLIT>
__global__ __launch_bounds__(256) void combine_kernel(
    const float* __restrict__ Opart, const float* __restrict__ lpart,
    float* __restrict__ out)
{
    const int row = blockIdx.x >> 2;                       // 0..127 = h*16+d
    const int n   = (blockIdx.x & 3) * 1024 + threadIdx.x * 4;
    const int h   = row >> 4;
    f32x4 osum = {0.f, 0.f, 0.f, 0.f}, lsum = {0.f, 0.f, 0.f, 0.f};
    #pragma unroll
    for (int s = 0; s < SPLIT; ++s) {
        osum += *(const f32x4*)&Opart[(s * 128 + row) * 4096 + n];
        lsum += *(const f32x4*)&lpart[(s * 8 + h) * 4096 + n];
    }
    f32x4 res;
    #pragma unroll
    for (int r = 0; r < 4; ++r) res[r] = osum[r] / lsum[r];
    *(f32x4*)&out[row * 4096 + n] = res;
}

// ---------------------------------------------------------------------------
extern "C" void kernel_launch(void* const* d_in, const int* in_sizes, int n_in,
                              void* d_out, int out_size, void* d_ws, size_t ws_size,
                              hipStream_t stream) {
    const float* x = (const float*)d_in[0];   // (128, 4096) fp32
    const float* w = (const float*)d_in[1];   // (384, 128) fp32
    float* out = (float*)d_out;               // (128, 4096) fp32

    char* ws = (char*)d_ws;
    short* qT = (short*)ws;                          // 1 MB
    short* kv = (short*)(ws + (1u << 20));           // 2 MB interleaved K|V

    constexpr int SPLIT = 8;
    const size_t opart_bytes = (size_t)SPLIT * 128 * 4096 * 4;   // 16 MB
    const size_t lpart_bytes = (size_t)SPLIT * 8 * 4096 * 4;     // 1 MB
    const size_t need_split  = (3ull << 20) + opart_bytes + lpart_bytes;

    dim3 gq(64, 8);
    qkv_kernel<<<gq, 256, 0, stream>>>(x, w, qT, kv);

    if (ws_size >= need_split) {
        float* Opart = (float*)(ws + (3ull << 20));
        float* lpart = (float*)(ws + (3ull << 20) + opart_bytes);
        attn_kernel<SPLIT><<<SPLIT * 256, 256, 0, stream>>>(qT, kv, Opart, lpart, out);
        combine_kernel<SPLIT><<<512, 256, 0, stream>>>(Opart, lpart, out);
    } else {
        attn_kernel<1><<<256, 256, 0, stream>>>(qT, kv, nullptr, nullptr, out);
    }
}